// Round 1
// baseline (23.567 us; speedup 1.0000x reference)
//
#include <hip/hip_runtime.h>

#define N_SAMPLES 128
#define NUM_POINTS 100000
#define GROUPS (NUM_POINTS / 4)   // 25000 groups of 4 points (48 B each)
#define BPS 16                    // blocks per sample
#define TPB 256

// Kernel A: zero the pm accumulators, compute the two translation losses.
__global__ __launch_bounds__(128) void t_loss_kernel(
    const float* __restrict__ gt_t, const float* __restrict__ pred_t,
    float* __restrict__ out)
{
    int n = threadIdx.x;
    if (n < N_SAMPLES) {
        float dx = fabsf(gt_t[n * 3 + 0] - pred_t[n * 3 + 0]);
        float dy = fabsf(gt_t[n * 3 + 1] - pred_t[n * 3 + 1]);
        float dz = fabsf(gt_t[n * 3 + 2] - pred_t[n * 3 + 2]);
        out[n] = 0.0f;                    // pm accumulator, filled by pm_kernel
        out[N_SAMPLES + n] = dx + dy;     // t_site_center_loss
        out[2 * N_SAMPLES + n] = dz;      // t_site_depth_loss
    }
}

// Kernel B: pm loss. grid = (BPS, N_SAMPLES). Each block reduces a chunk of
// points for one sample and atomicAdds the scaled partial into out[n].
__global__ __launch_bounds__(TPB) void pm_kernel(
    const int* __restrict__ obj_id,
    const float* __restrict__ gtR, const float* __restrict__ prR,
    const float* __restrict__ pts, const float* __restrict__ diam,
    float* __restrict__ out)
{
    const int n = blockIdx.y;       // sample index (block-uniform)
    const int chunk = blockIdx.x;   // 0..BPS-1
    const int oid = obj_id[n];

    float dr0 = prR[n * 9 + 0] - gtR[n * 9 + 0];
    float dr1 = prR[n * 9 + 1] - gtR[n * 9 + 1];
    float dr2 = prR[n * 9 + 2] - gtR[n * 9 + 2];
    float dr3 = prR[n * 9 + 3] - gtR[n * 9 + 3];
    float dr4 = prR[n * 9 + 4] - gtR[n * 9 + 4];
    float dr5 = prR[n * 9 + 5] - gtR[n * 9 + 5];
    float dr6 = prR[n * 9 + 6] - gtR[n * 9 + 6];
    float dr7 = prR[n * 9 + 7] - gtR[n * 9 + 7];
    float dr8 = prR[n * 9 + 8] - gtR[n * 9 + 8];

    const float4* __restrict__ p4 =
        (const float4*)(pts + (size_t)oid * (size_t)NUM_POINTS * 3);

    float sum = 0.0f;
    for (int g = chunk * TPB + threadIdx.x; g < GROUPS; g += BPS * TPB) {
        float4 a = p4[g * 3 + 0];
        float4 b = p4[g * 3 + 1];
        float4 c = p4[g * 3 + 2];
        // 4 points packed in 12 floats:
        // p0=(a.x,a.y,a.z) p1=(a.w,b.x,b.y) p2=(b.z,b.w,c.x) p3=(c.y,c.z,c.w)
        sum += fabsf(dr0 * a.x + dr1 * a.y + dr2 * a.z)
             + fabsf(dr3 * a.x + dr4 * a.y + dr5 * a.z)
             + fabsf(dr6 * a.x + dr7 * a.y + dr8 * a.z);
        sum += fabsf(dr0 * a.w + dr1 * b.x + dr2 * b.y)
             + fabsf(dr3 * a.w + dr4 * b.x + dr5 * b.y)
             + fabsf(dr6 * a.w + dr7 * b.x + dr8 * b.y);
        sum += fabsf(dr0 * b.z + dr1 * b.w + dr2 * c.x)
             + fabsf(dr3 * b.z + dr4 * b.w + dr5 * c.x)
             + fabsf(dr6 * b.z + dr7 * b.w + dr8 * c.x);
        sum += fabsf(dr0 * c.y + dr1 * c.z + dr2 * c.w)
             + fabsf(dr3 * c.y + dr4 * c.z + dr5 * c.w)
             + fabsf(dr6 * c.y + dr7 * c.z + dr8 * c.w);
    }

    // wave64 butterfly reduce
    #pragma unroll
    for (int off = 32; off > 0; off >>= 1)
        sum += __shfl_down(sum, off, 64);

    __shared__ float wsum[TPB / 64];
    const int lane = threadIdx.x & 63;
    const int wave = threadIdx.x >> 6;
    if (lane == 0) wsum[wave] = sum;
    __syncthreads();
    if (threadIdx.x == 0) {
        float s = wsum[0] + wsum[1] + wsum[2] + wsum[3];
        float scale = 1.0f / ((float)NUM_POINTS * diam[oid]);
        atomicAdd(&out[n], s * scale);
    }
}

extern "C" void kernel_launch(void* const* d_in, const int* in_sizes, int n_in,
                              void* d_out, int out_size, void* d_ws, size_t ws_size,
                              hipStream_t stream) {
    const int*   obj_id = (const int*)d_in[0];
    const float* gtR    = (const float*)d_in[1];
    const float* prR    = (const float*)d_in[2];
    const float* gt_t   = (const float*)d_in[3];
    const float* pred_t = (const float*)d_in[4];
    const float* pts    = (const float*)d_in[5];
    const float* diam   = (const float*)d_in[6];
    float* out = (float*)d_out;

    t_loss_kernel<<<1, 128, 0, stream>>>(gt_t, pred_t, out);
    pm_kernel<<<dim3(BPS, N_SAMPLES), TPB, 0, stream>>>(
        obj_id, gtR, prR, pts, diam, out);
}